// Round 5
// baseline (91.420 us; speedup 1.0000x reference)
//
#include <hip/hip_runtime.h>
#include <hip/hip_bf16.h>

// PraxisMemory: one-shot delta-rule memory. B=4,H=16,S=4096,D=64, all f32 I/O.
//
// Gram reformulation:  M = W0 + sigma_k^T @ VU
//                        = W0 + sigma_k^T @ V - (sigma_k^T diag(1/den) sigma_k) @ W0
//                        = W0 + MP1 - G @ W0
// k1: per (bh, split, d-strip) single-wave block: accumulate MP1, G, z with pure
//     gather loads + MFMA. 64-thread blocks + launch_bounds(64,4) -> up to 512
//     VGPR/wave so ALL chunk loads stay in flight (deep MLP), no barriers.
// k_reduce: M = W0 + sum_p Mpart -> MfinT bf16; z = z0 + sum Zpart.
// k2: one 32-row group per single-wave block: out = O + gate*(sq@M/norm - O).

#define B_  4
#define H_  16
#define S_  4096
#define D_  64
#define BH_ 64
#define EPS_ 1e-8f

typedef __attribute__((ext_vector_type(8))) short bf16x8;
typedef __attribute__((ext_vector_type(4))) float f32x4;
typedef __attribute__((ext_vector_type(4))) unsigned short u16x4;

__device__ __forceinline__ unsigned short f2bf(float x) {
    union { float f; unsigned u; } v; v.f = x;
    return (unsigned short)((v.u + 0x7FFFu + ((v.u >> 16) & 1u)) >> 16);  // RTNE
}
__device__ __forceinline__ float elup1(float x) {
    return x > 0.0f ? x + 1.0f : __expf(x);  // elu(x)+1
}
__device__ __forceinline__ f32x4 fzero() { f32x4 z = {0.f, 0.f, 0.f, 0.f}; return z; }

// ---------------------------------------------------------------------------
// Kernel 1: single-wave blocks. blockIdx = ((bh*NS + p) * 4 + w); wave owns
// d-strip [16w, 16w+16).
// MFMA 16x16x32 bf16 conventions (verified by passing rounds):
//   A-frag: lane m = l&15, per-lane k = (l>>4)*8 + j
//   B-frag: lane n = l&15, same k bijection
//   C/D:    lane l, reg r -> row m = (l>>4)*4 + r, col n = l&15
// Gather layout: lane (c16,g4) holds X[s = row0 + g4*8 + j][column];
// strip q's column = ((w+q)&3)*16 + c16 so q=0 is the wave's own strip
// (compile-time register indexing).
// ---------------------------------------------------------------------------
__global__ __launch_bounds__(64, 4) void k1_states(
    const float* __restrict__ Kp, const float* __restrict__ Vp,
    const float* __restrict__ W0, const float* __restrict__ Z0,
    float* __restrict__ Mpart, float* __restrict__ Zpart, int NS)
{
    const int bid = blockIdx.x;
    const int w   = bid & 3;
    const int t2  = bid >> 2;
    const int bh  = t2 / NS;
    const int p   = t2 % NS;
    const int h   = bh & (H_ - 1);
    const int lane = threadIdx.x;
    const int c16  = lane & 15;
    const int g4   = lane >> 4;

    __shared__ float Glds[16][68];   // wave-private slab (4.4 KiB)

    int   col[4];
    float z0l[4];
    #pragma unroll
    for (int q = 0; q < 4; ++q) {
        col[q] = (((w + q) & 3) << 4) + c16;
        z0l[q] = Z0[h * 64 + col[q]];
    }

    bf16x8 ones;
    #pragma unroll
    for (int j = 0; j < 8; ++j) ones[j] = (short)0x3F80;  // bf16 1.0

    const size_t base   = (size_t)bh * S_ * D_;
    const int    schunk = S_ / NS;
    const int    nch    = schunk >> 5;   // 32-row chunks in this split

    f32x4 mp1[4], gac[4], zac = fzero();
    #pragma unroll
    for (int i = 0; i < 4; ++i) { mp1[i] = fzero(); gac[i] = fzero(); }

    auto do_chunk = [&](int c) {
        const float* kr = Kp + base + (size_t)(p * schunk + c * 32) * D_;
        const float* vr = Vp + base + (size_t)(p * schunk + c * 32) * D_;

        // ---- gather K^T strips (64B segments; all independent) ----
        float kf[4][8];
        #pragma unroll
        for (int q = 0; q < 4; ++q)
        #pragma unroll
        for (int j = 0; j < 8; ++j)
            kf[q][j] = kr[(g4 * 8 + j) * 64 + col[q]];

        // ---- gather V^T strips (issue before any dependent math) ----
        float vf[4][8];
        #pragma unroll
        for (int nt = 0; nt < 4; ++nt)
        #pragma unroll
        for (int j = 0; j < 8; ++j)
            vf[nt][j] = vr[(g4 * 8 + j) * 64 + nt * 16 + c16];

        // ---- sigma + den partials ----
        float den[8];
        #pragma unroll
        for (int j = 0; j < 8; ++j) den[j] = 0.f;
        #pragma unroll
        for (int q = 0; q < 4; ++q)
        #pragma unroll
        for (int j = 0; j < 8; ++j) {
            float s = elup1(kf[q][j]);
            kf[q][j] = s;
            den[j] += s * z0l[q];
        }
        #pragma unroll
        for (int j = 0; j < 8; ++j) {
            float d = den[j];
            d += __shfl_xor(d, 1); d += __shfl_xor(d, 2);
            d += __shfl_xor(d, 4); d += __shfl_xor(d, 8);
            den[j] = __builtin_amdgcn_rcpf(d + EPS_);   // rd
        }

        // ---- fragments: own strip unscaled (A), all strips scaled (G's B) ----
        bf16x8 aown, skbS[4];
        #pragma unroll
        for (int j = 0; j < 8; ++j) aown[j] = (short)f2bf(kf[0][j]);
        #pragma unroll
        for (int q = 0; q < 4; ++q)
        #pragma unroll
        for (int j = 0; j < 8; ++j)
            skbS[q][j] = (short)f2bf(kf[q][j] * den[j]);

        bf16x8 vbf[4];
        #pragma unroll
        for (int nt = 0; nt < 4; ++nt)
        #pragma unroll
        for (int j = 0; j < 8; ++j) vbf[nt][j] = (short)f2bf(vf[nt][j]);

        // ---- 9 MFMAs ----
        zac = __builtin_amdgcn_mfma_f32_16x16x32_bf16(aown, ones, zac, 0, 0, 0);
        #pragma unroll
        for (int nt = 0; nt < 4; ++nt)
            mp1[nt] = __builtin_amdgcn_mfma_f32_16x16x32_bf16(aown, vbf[nt], mp1[nt], 0, 0, 0);
        #pragma unroll
        for (int q = 0; q < 4; ++q)
            gac[q] = __builtin_amdgcn_mfma_f32_16x16x32_bf16(aown, skbS[q], gac[q], 0, 0, 0);
    };

    // paired chunks: both bodies' loads can hoist together (deep MLP)
    #pragma unroll 1
    for (int c = w; c < nch; c += 8) {
        do_chunk(c);
        if (c + 4 < nch) do_chunk(c + 4);
    }

    // ================= epilogue (wave-private, barrier-free) =================
    // 1. G tiles -> LDS (cols at global d' position)
    #pragma unroll
    for (int q = 0; q < 4; ++q)
    #pragma unroll
    for (int r = 0; r < 4; ++r)
        Glds[g4 * 4 + r][(((w + q) & 3) << 4) + c16] = gac[q][r];

    // 2. read G back as A-frags: A[m=d(in-strip)][k=d']
    bf16x8 ag[2];
    #pragma unroll
    for (int kk = 0; kk < 2; ++kk)
    #pragma unroll
    for (int j = 0; j < 8; ++j)
        ag[kk][j] = (short)f2bf(Glds[c16][kk * 32 + g4 * 8 + j]);

    // 3. GW0 tiles: B-frag from W0[d'][e] gathers (L2-resident)
    f32x4 gw[4];
    #pragma unroll
    for (int nt = 0; nt < 4; ++nt) {
        f32x4 t = fzero();
        #pragma unroll
        for (int kk = 0; kk < 2; ++kk) {
            bf16x8 wb;
            #pragma unroll
            for (int j = 0; j < 8; ++j)
                wb[j] = (short)f2bf(W0[(size_t)h * 4096 + (kk * 32 + g4 * 8 + j) * 64 + nt * 16 + c16]);
            t = __builtin_amdgcn_mfma_f32_16x16x32_bf16(ag[kk], wb, t, 0, 0, 0);
        }
        gw[nt] = t;
    }

    // 4. stage M slab (MP1 - GW0) in LDS, then fully-coalesced f32x4 stores
    #pragma unroll
    for (int nt = 0; nt < 4; ++nt)
    #pragma unroll
    for (int r = 0; r < 4; ++r)
        Glds[g4 * 4 + r][nt * 16 + c16] = mp1[nt][r] - gw[nt][r];

    float* mout = Mpart + ((size_t)p * BH_ + bh) * 4096 + w * 1024;
    #pragma unroll
    for (int q2 = 0; q2 < 4; ++q2) {
        f32x4 v = *(const f32x4*)&Glds[q2 * 4 + g4][c16 * 4];
        *(f32x4*)(mout + q2 * 256 + lane * 4) = v;
    }

    // 5. z
    if (c16 == 0) {
        #pragma unroll
        for (int r = 0; r < 4; ++r)
            Zpart[((size_t)p * BH_ + bh) * 64 + w * 16 + g4 * 4 + r] = zac[r];
    }
}

// ---------------------------------------------------------------------------
// Reduce: M = W0 + sum_p Mpart -> MfinT bf16 [bh][e*64+d]; z = z0 + sum Zpart.
// Grid = BH_*4 blocks; block handles d-rows [q*16, q*16+16).
// ---------------------------------------------------------------------------
__global__ void k_reduce(const float* __restrict__ Mpart, const float* __restrict__ Zpart,
                         const float* __restrict__ W0, const float* __restrict__ Z0,
                         unsigned short* __restrict__ MfinT, float* __restrict__ Zfin, int NS)
{
    const int bh = blockIdx.x >> 2, q = blockIdx.x & 3;
    const int h = bh & (H_ - 1), t = threadIdx.x;
    __shared__ float Ml[16][65];

    const int o = q * 1024 + t * 4;          // linear d*64+e
    f32x4 s = *(const f32x4*)(W0 + (size_t)h * 4096 + o);
    for (int p = 0; p < NS; ++p)
        s = s + *(const f32x4*)(Mpart + ((size_t)p * BH_ + bh) * 4096 + o);
    const int dl = t >> 4, e0 = (t & 15) * 4;
    #pragma unroll
    for (int j = 0; j < 4; ++j) Ml[dl][e0 + j] = s[j];
    __syncthreads();

    const int e = t >> 2, dd0 = (t & 3) * 4;
    u16x4 w;
    #pragma unroll
    for (int j = 0; j < 4; ++j) w[j] = f2bf(Ml[dd0 + j][e]);
    *(u16x4*)(MfinT + (size_t)bh * 4096 + e * 64 + q * 16 + dd0) = w;

    if (q == 0 && t < 64) {
        float zs = Z0[h * 64 + t];
        for (int p = 0; p < NS; ++p) zs += Zpart[((size_t)p * BH_ + bh) * 64 + t];
        Zfin[bh * 64 + t] = zs;
    }
}

// ---------------------------------------------------------------------------
// Kernel 2: single-wave blocks, one 32-row group each. Grid = BH_*128.
// RET^T = M^T @ SQ^T ; out = O + gate*(RET/norm - O). No LDS.
// ---------------------------------------------------------------------------
__global__ __launch_bounds__(64, 4) void k2_out(
    const float* __restrict__ Qp, const float* __restrict__ Op,
    const float* __restrict__ Bp, const unsigned short* __restrict__ MfinT,
    const float* __restrict__ Zfin, float* __restrict__ Out)
{
    const int bid = blockIdx.x;
    const int bh  = bid >> 7;
    const int g   = bid & 127;
    const int h   = bh & (H_ - 1);
    const int lane = threadIdx.x;
    const int c16 = lane & 15, g4 = lane >> 4;
    const int row0 = g * 32;
    const size_t base = (size_t)bh * S_ * D_;

    // ---- Q loads first (HBM; deepest latency) ----
    float sq[2][2][8];
    #pragma unroll
    for (int st = 0; st < 2; ++st) {
        const float* qr = Qp + base + (size_t)(row0 + st * 16 + c16) * D_;
        #pragma unroll
        for (int kk = 0; kk < 2; ++kk) {
            f32x4 a = *(const f32x4*)(qr + kk * 32 + g4 * 8);
            f32x4 b = *(const f32x4*)(qr + kk * 32 + g4 * 8 + 4);
            #pragma unroll
            for (int j = 0; j < 4; ++j) {
                sq[st][kk][j]     = a[j];
                sq[st][kk][4 + j] = b[j];
            }
        }
    }

    // ---- O loads (HBM) ----
    f32x4 o4[2][4];
    #pragma unroll
    for (int st = 0; st < 2; ++st) {
        const float* orow = Op + base + (size_t)(row0 + st * 16 + c16) * D_;
        #pragma unroll
        for (int et = 0; et < 4; ++et)
            o4[st][et] = *(const f32x4*)(orow + et * 16 + g4 * 4);
    }

    // ---- prologue (L2-resident): mz, M^T frags, gate ----
    float mzv[2][8];
    #pragma unroll
    for (int kk = 0; kk < 2; ++kk) {
        f32x4 a = *(const f32x4*)(Zfin + bh * 64 + kk * 32 + g4 * 8);
        f32x4 b = *(const f32x4*)(Zfin + bh * 64 + kk * 32 + g4 * 8 + 4);
        #pragma unroll
        for (int j = 0; j < 4; ++j) { mzv[kk][j] = a[j]; mzv[kk][4 + j] = b[j]; }
    }
    bf16x8 mf[4][2];
    #pragma unroll
    for (int et = 0; et < 4; ++et)
    #pragma unroll
    for (int kk = 0; kk < 2; ++kk)
        mf[et][kk] = *(const bf16x8*)(MfinT + (size_t)bh * 4096 + (et * 16 + c16) * 64 + kk * 32 + g4 * 8);
    float gate[4][4];
    #pragma unroll
    for (int et = 0; et < 4; ++et)
    #pragma unroll
    for (int r = 0; r < 4; ++r) {
        float b = Bp[h * 64 + et * 16 + g4 * 4 + r];
        gate[et][r] = 1.0f / (1.0f + __expf(-b));
    }

    // ---- sigma_q + norm ----
    float n0 = 0.f, n1 = 0.f;
    #pragma unroll
    for (int st = 0; st < 2; ++st)
    #pragma unroll
    for (int kk = 0; kk < 2; ++kk)
    #pragma unroll
    for (int j = 0; j < 8; ++j) {
        float s = elup1(sq[st][kk][j]);
        sq[st][kk][j] = s;
        if (st == 0) n0 += s * mzv[kk][j]; else n1 += s * mzv[kk][j];
    }
    n0 += __shfl_xor(n0, 16); n0 += __shfl_xor(n0, 32);
    n1 += __shfl_xor(n1, 16); n1 += __shfl_xor(n1, 32);
    const float rn0 = __builtin_amdgcn_rcpf(n0 + EPS_);
    const float rn1 = __builtin_amdgcn_rcpf(n1 + EPS_);

    bf16x8 sqf[2][2];
    #pragma unroll
    for (int st = 0; st < 2; ++st)
    #pragma unroll
    for (int kk = 0; kk < 2; ++kk) {
        bf16x8 f;
        #pragma unroll
        for (int j = 0; j < 8; ++j) f[j] = (short)f2bf(sq[st][kk][j]);
        sqf[st][kk] = f;
    }

    f32x4 acc[2][4];
    #pragma unroll
    for (int st = 0; st < 2; ++st)
    #pragma unroll
    for (int et = 0; et < 4; ++et) {
        f32x4 t = __builtin_amdgcn_mfma_f32_16x16x32_bf16(mf[et][0], sqf[st][0], fzero(), 0, 0, 0);
        acc[st][et] = __builtin_amdgcn_mfma_f32_16x16x32_bf16(mf[et][1], sqf[st][1], t, 0, 0, 0);
    }

    #pragma unroll
    for (int st = 0; st < 2; ++st) {
        const float rn = st ? rn1 : rn0;
        const size_t roff = base + (size_t)(row0 + st * 16 + c16) * D_;
        #pragma unroll
        for (int et = 0; et < 4; ++et) {
            f32x4 wv;
            #pragma unroll
            for (int r = 0; r < 4; ++r) {
                float t = acc[st][et][r] * rn;
                wv[r] = o4[st][et][r] + gate[et][r] * (t - o4[st][et][r]);
            }
            *(f32x4*)(Out + roff + et * 16 + g4 * 4) = wv;
        }
    }
}

// ---------------------------------------------------------------------------
extern "C" void kernel_launch(void* const* d_in, const int* in_sizes, int n_in,
                              void* d_out, int out_size, void* d_ws, size_t ws_size,
                              hipStream_t stream)
{
    const float* Q  = (const float*)d_in[0];
    const float* K  = (const float*)d_in[1];
    const float* V  = (const float*)d_in[2];
    const float* O  = (const float*)d_in[3];
    const float* Bt = (const float*)d_in[4];
    const float* W0 = (const float*)d_in[5];
    const float* Z0 = (const float*)d_in[6];
    float* Out = (float*)d_out;

    // ws: [Mpart NS*64*4096 f32][Zpart NS*64*64 f32][Zfin 64*64 f32][MfinT 64*4096 bf16]
    int NS = 16;
    auto need = [](int ns) -> size_t {
        return sizeof(float) * ((size_t)ns * BH_ * 4096 + (size_t)ns * BH_ * 64 + BH_ * 64) +
               sizeof(unsigned short) * (size_t)BH_ * 4096;
    };
    while (NS > 1 && need(NS) > ws_size) NS >>= 1;

    float* Mpart = (float*)d_ws;
    float* Zpart = Mpart + (size_t)NS * BH_ * 4096;
    float* Zfin  = Zpart + (size_t)NS * BH_ * 64;
    unsigned short* MfinT = (unsigned short*)(Zfin + (size_t)BH_ * 64);

    hipLaunchKernelGGL(k1_states, dim3(BH_ * NS * 4), dim3(64), 0, stream,
                       K, V, W0, Z0, Mpart, Zpart, NS);
    hipLaunchKernelGGL(k_reduce, dim3(BH_ * 4), dim3(256), 0, stream,
                       Mpart, Zpart, W0, Z0, MfinT, Zfin, NS);
    hipLaunchKernelGGL(k2_out, dim3(BH_ * 128), dim3(64), 0, stream,
                       Q, O, Bt, MfinT, Zfin, Out);
}